// Round 2
// baseline (6557.813 us; speedup 1.0000x reference)
//
#include <hip/hip_runtime.h>
#include <hip/hip_bf16.h>

#define N_NODES  200000
#define N_EDGES  6400000
#define N_GRAPHS 512
#define DIM_IN   128
#define HID      32
#define BN_EPS   1e-5f

// chunked scan params
#define CHUNK    2048
#define NCHUNKS  98   // ceil(200000/2048)

typedef const float* fp;

// ---------------- CSR build ----------------

__global__ void k_hist(const int* __restrict__ dst, int* __restrict__ deg) {
    int i = blockIdx.x * blockDim.x + threadIdx.x;
    int stride = gridDim.x * blockDim.x;
    for (; i < N_EDGES; i += stride) atomicAdd(&deg[dst[i]], 1);
}

__global__ void k_chunksum(const int* __restrict__ deg, int* __restrict__ chunksum) {
    __shared__ int red[256];
    int b = blockIdx.x, t = threadIdx.x;
    int base = b * CHUNK;
    int s = 0;
    for (int k = 0; k < 8; ++k) {
        int i = base + t + k * 256;
        if (i < N_NODES) s += deg[i];
    }
    red[t] = s; __syncthreads();
    for (int off = 128; off > 0; off >>= 1) {
        if (t < off) red[t] += red[t + off];
        __syncthreads();
    }
    if (t == 0) chunksum[b] = red[0];
}

__global__ void k_scanchunks(const int* __restrict__ chunksum, int* __restrict__ chunkoff,
                             int* __restrict__ rowptr) {
    __shared__ int buf[128];
    int t = threadIdx.x;  // 128 threads
    int v = (t < NCHUNKS) ? chunksum[t] : 0;
    buf[t] = v; __syncthreads();
    for (int off = 1; off < 128; off <<= 1) {
        int add = (t >= off) ? buf[t - off] : 0;
        __syncthreads();
        buf[t] += add;
        __syncthreads();
    }
    if (t < NCHUNKS) chunkoff[t] = buf[t] - v;  // exclusive
    if (t == 0) rowptr[N_NODES] = N_EDGES;      // every edge has valid dst
}

__global__ void k_scanfinal(const int* __restrict__ deg, const int* __restrict__ chunkoff,
                            int* __restrict__ rowptr, int* __restrict__ fillpos) {
    __shared__ int tsum[256];
    int b = blockIdx.x, t = threadIdx.x;
    int base = b * CHUNK + t * 8;
    int v[8]; int s = 0;
    for (int k = 0; k < 8; ++k) {
        int i = base + k;
        v[k] = (i < N_NODES) ? deg[i] : 0;
        s += v[k];
    }
    tsum[t] = s; __syncthreads();
    for (int off = 1; off < 256; off <<= 1) {
        int add = (t >= off) ? tsum[t - off] : 0;
        __syncthreads();
        tsum[t] += add;
        __syncthreads();
    }
    int run = tsum[t] - s + chunkoff[b];
    for (int k = 0; k < 8; ++k) {
        int i = base + k;
        if (i < N_NODES) { rowptr[i] = run; fillpos[i] = run; run += v[k]; }
    }
}

__global__ void k_fill(const int* __restrict__ src, const int* __restrict__ dst,
                       int* __restrict__ fillpos, int* __restrict__ csr) {
    int i = blockIdx.x * blockDim.x + threadIdx.x;
    int stride = gridDim.x * blockDim.x;
    for (; i < N_EDGES; i += stride) {
        int d = dst[i];
        int pos = atomicAdd(&fillpos[d], 1);
        csr[pos] = src[i];
    }
}

__global__ void k_bounds(const int* __restrict__ batch, int* __restrict__ gstart) {
    int g = blockIdx.x * blockDim.x + threadIdx.x;
    if (g > N_GRAPHS) return;
    if (g == N_GRAPHS) { gstart[g] = N_NODES; return; }
    int lo = 0, hi = N_NODES;
    while (lo < hi) {
        int mid = (lo + hi) >> 1;
        if (batch[mid] < g) lo = mid + 1; else hi = mid;
    }
    gstart[g] = lo;
}

// ---------------- GIN layers ----------------

// 32-dim input layer: half-wave (32 lanes) per node, lane = feature/out-col.
// Computes a = relu(relu((h+agg)@w1+b1)@w2+b2), writes abuf, accumulates BN stats.
__global__ __launch_bounds__(256) void k_agg32(
    const float* __restrict__ hin, const int* __restrict__ rowptr,
    const int* __restrict__ csr, fp w1, fp b1, fp w2, fp b2,
    float* __restrict__ aout, float* __restrict__ stats)
{
    const int lane = threadIdx.x & 63;
    const int c = lane & 31;
    const int srcBase = lane & 32;
    float w1r[32], w2r[32];
    #pragma unroll
    for (int k = 0; k < 32; ++k) {
        w1r[k] = w1[k * 32 + c];
        w2r[k] = w2[k * 32 + c];
    }
    const float b1c = b1[c];
    const float b2c = b2[c];

    int worker   = (blockIdx.x * blockDim.x + threadIdx.x) >> 5;
    int nworkers = (gridDim.x * blockDim.x) >> 5;
    float s1 = 0.f, s2 = 0.f;

    for (int n = worker; n < N_NODES; n += nworkers) {
        float acc = hin[n * 32 + c];
        int e0 = rowptr[n], e1 = rowptr[n + 1];
        int e = e0;
        for (; e + 3 < e1; e += 4) {
            int s0 = csr[e], sA = csr[e + 1], sB = csr[e + 2], sC = csr[e + 3];
            float v0 = hin[s0 * 32 + c];
            float v1 = hin[sA * 32 + c];
            float v2 = hin[sB * 32 + c];
            float v3 = hin[sC * 32 + c];
            acc += (v0 + v1) + (v2 + v3);
        }
        for (; e < e1; ++e) acc += hin[csr[e] * 32 + c];

        float acc1 = b1c;
        #pragma unroll
        for (int k = 0; k < 32; ++k) {
            float v = __shfl(acc, srcBase | k, 64);
            acc1 = fmaf(v, w1r[k], acc1);
        }
        float h3 = fmaxf(acc1, 0.f);
        float acc2 = b2c;
        #pragma unroll
        for (int k = 0; k < 32; ++k) {
            float v = __shfl(h3, srcBase | k, 64);
            acc2 = fmaf(v, w2r[k], acc2);
        }
        float a = fmaxf(acc2, 0.f);
        aout[n * 32 + c] = a;
        s1 += a; s2 += a * a;
    }
    // combine the two half-waves (same feature c, different nodes)
    s1 += __shfl_xor(s1, 32, 64);
    s2 += __shfl_xor(s2, 32, 64);
    __shared__ float ls1[4][32], ls2[4][32];
    int w = threadIdx.x >> 6;
    if ((threadIdx.x & 32) == 0) { ls1[w][c] = s1; ls2[w][c] = s2; }
    __syncthreads();
    if (threadIdx.x < 32) {
        float t1 = ls1[0][c] + ls1[1][c] + ls1[2][c] + ls1[3][c];
        float t2 = ls2[0][c] + ls2[1][c] + ls2[2][c] + ls2[3][c];
        atomicAdd(&stats[c], t1);
        atomicAdd(&stats[32 + c], t2);
    }
}

// 128-dim input (encoder layer 0): full wave per node, lane holds feature pair (2l,2l+1).
__global__ __launch_bounds__(256) void k_agg128(
    const float* __restrict__ x, const int* __restrict__ rowptr,
    const int* __restrict__ csr, fp w1 /*[128][32]*/, fp b1, fp w2, fp b2,
    float* __restrict__ aout, float* __restrict__ stats)
{
    __shared__ float w1s[DIM_IN * 32];  // 16 KiB
    for (int i = threadIdx.x; i < DIM_IN * 32; i += 256)
        w1s[i] = w1[i];
    const int lane = threadIdx.x & 63;
    const int c = lane & 31;
    const int srcBase = lane & 32;
    float w2r[32];
    #pragma unroll
    for (int k = 0; k < 32; ++k) w2r[k] = w2[k * 32 + c];
    const float b1c = b1[c];
    const float b2c = b2[c];
    __syncthreads();

    const float2* x2 = reinterpret_cast<const float2*>(x);  // 64 pairs per row
    int worker   = (blockIdx.x * blockDim.x + threadIdx.x) >> 6;
    int nworkers = (gridDim.x * blockDim.x) >> 6;
    float s1 = 0.f, s2 = 0.f;

    for (int n = worker; n < N_NODES; n += nworkers) {
        float2 p = x2[n * 64 + lane];
        float a0 = p.x, a1 = p.y;
        int e0 = rowptr[n], e1 = rowptr[n + 1];
        int e = e0;
        for (; e + 1 < e1; e += 2) {
            int sA = csr[e], sB = csr[e + 1];
            float2 qa = x2[sA * 64 + lane];
            float2 qb = x2[sB * 64 + lane];
            a0 += qa.x + qb.x; a1 += qa.y + qb.y;
        }
        for (; e < e1; ++e) {
            float2 q = x2[csr[e] * 64 + lane];
            a0 += q.x; a1 += q.y;
        }
        float acc1 = b1c;
        #pragma unroll
        for (int k = 0; k < 64; ++k) {
            float v0 = __shfl(a0, k, 64);
            float v1 = __shfl(a1, k, 64);
            acc1 = fmaf(v0, w1s[(2 * k) * 32 + c], acc1);
            acc1 = fmaf(v1, w1s[(2 * k + 1) * 32 + c], acc1);
        }
        float h3 = fmaxf(acc1, 0.f);
        float acc2 = b2c;
        #pragma unroll
        for (int k = 0; k < 32; ++k) {
            float v = __shfl(h3, srcBase | k, 64);
            acc2 = fmaf(v, w2r[k], acc2);
        }
        float a = fmaxf(acc2, 0.f);
        if (lane < 32) {
            aout[n * 32 + c] = a;
            s1 += a; s2 += a * a;
        }
    }
    __shared__ float ls1[4][32], ls2[4][32];
    int w = threadIdx.x >> 6;
    if (lane < 32) { ls1[w][c] = s1; ls2[w][c] = s2; }
    __syncthreads();
    if (threadIdx.x < 32) {
        float t1 = ls1[0][c] + ls1[1][c] + ls1[2][c] + ls1[3][c];
        float t2 = ls2[0][c] + ls2[1][c] + ls2[2][c] + ls2[3][c];
        atomicAdd(&stats[c], t1);
        atomicAdd(&stats[32 + c], t2);
    }
}

// BatchNorm apply: hout = gamma*(a-m)/sqrt(v+eps)+beta; optional fp32 mirror to d_out.
__global__ void k_bn(const float* __restrict__ a, const float* __restrict__ stats,
                     fp gamma, fp beta, float* __restrict__ hout,
                     float* __restrict__ out_mirror)
{
    const int c = threadIdx.x & 31;
    float m  = stats[c] * (1.f / N_NODES);
    float vv = stats[32 + c] * (1.f / N_NODES) - m * m;
    float sc = gamma[c] / sqrtf(vv + BN_EPS);
    float sh = beta[c] - m * sc;
    int i = blockIdx.x * blockDim.x + threadIdx.x;
    int stride = gridDim.x * blockDim.x;  // multiple of 32 -> (i&31)==c always
    for (; i < N_NODES * 32; i += stride) {
        float val = fmaf(a[i], sc, sh);
        hout[i] = val;
        if (out_mirror) out_mirror[i] = val;
    }
}

// Global add-pool of one encoder layer into d_out global_rep slice (batch is sorted).
__global__ void k_pool(const float* __restrict__ h, const int* __restrict__ gstart,
                       float* __restrict__ out, int col0)
{
    int g = blockIdx.x;
    int t = threadIdx.x;
    int f = t & 31, j = t >> 5;  // 8 node-groups x 32 features
    int n0 = gstart[g], n1 = gstart[g + 1];
    float s = 0.f;
    for (int n = n0 + j; n < n1; n += 8) s += h[n * 32 + f];
    __shared__ float red[8][32];
    red[j][f] = s; __syncthreads();
    if (t < 32) {
        float tot = 0.f;
        #pragma unroll
        for (int k = 0; k < 8; ++k) tot += red[k][f];
        out[g * (5 * HID) + col0 + f] = tot;
    }
}

// Decoder last layer: 32 -> 32 -> 128, relu, no BN, fp32 out. Full wave per node.
__global__ __launch_bounds__(256) void k_dec_last(
    const float* __restrict__ hin, const int* __restrict__ rowptr,
    const int* __restrict__ csr, fp w1, fp b1, fp w2 /*[32][128]*/, fp b2,
    float* __restrict__ out)
{
    const int lane = threadIdx.x & 63;
    const int c = lane & 31;
    float w1r[32], w2a[32], w2b[32];
    #pragma unroll
    for (int k = 0; k < 32; ++k) {
        w1r[k] = w1[k * 32 + c];
        w2a[k] = w2[k * 128 + 2 * lane];
        w2b[k] = w2[k * 128 + 2 * lane + 1];
    }
    const float b1c = b1[c];
    const float b2a = b2[2 * lane];
    const float b2b = b2[2 * lane + 1];

    int worker   = (blockIdx.x * blockDim.x + threadIdx.x) >> 6;
    int nworkers = (gridDim.x * blockDim.x) >> 6;

    for (int n = worker; n < N_NODES; n += nworkers) {
        // both half-waves compute identical acc (c repeats); cache lines shared
        float acc = hin[n * 32 + c];
        int e0 = rowptr[n], e1 = rowptr[n + 1];
        int e = e0;
        for (; e + 3 < e1; e += 4) {
            int s0 = csr[e], sA = csr[e + 1], sB = csr[e + 2], sC = csr[e + 3];
            float v0 = hin[s0 * 32 + c];
            float v1 = hin[sA * 32 + c];
            float v2 = hin[sB * 32 + c];
            float v3 = hin[sC * 32 + c];
            acc += (v0 + v1) + (v2 + v3);
        }
        for (; e < e1; ++e) acc += hin[csr[e] * 32 + c];

        float acc1 = b1c;
        #pragma unroll
        for (int k = 0; k < 32; ++k) {
            float v = __shfl(acc, k, 64);  // h2 lives (duplicated) in lanes 0..31
            acc1 = fmaf(v, w1r[k], acc1);
        }
        float h3 = fmaxf(acc1, 0.f);  // duplicated in both halves
        float oa = b2a, ob = b2b;
        #pragma unroll
        for (int k = 0; k < 32; ++k) {
            float v = __shfl(h3, (lane & 32) | k, 64);
            oa = fmaf(v, w2a[k], oa);
            ob = fmaf(v, w2b[k], ob);
        }
        oa = fmaxf(oa, 0.f); ob = fmaxf(ob, 0.f);
        float2 pr; pr.x = oa; pr.y = ob;
        reinterpret_cast<float2*>(out)[n * 64 + lane] = pr;
    }
}

// ---------------- launch ----------------

extern "C" void kernel_launch(void* const* d_in, const int* in_sizes, int n_in,
                              void* d_out, int out_size, void* d_ws, size_t ws_size,
                              hipStream_t stream) {
    fp         x        = (fp)d_in[0];
    const int* edge     = (const int*)d_in[1];
    const int* batch    = (const int*)d_in[2];
    fp e0_w1 = (fp)d_in[3],  e0_b1 = (fp)d_in[4];
    fp e0_w2 = (fp)d_in[5],  e0_b2 = (fp)d_in[6];
    fp enc_w1 = (fp)d_in[7],  enc_b1 = (fp)d_in[8];
    fp enc_w2 = (fp)d_in[9],  enc_b2 = (fp)d_in[10];
    fp enc_gamma = (fp)d_in[11], enc_beta = (fp)d_in[12];
    fp dec_w1 = (fp)d_in[13], dec_b1 = (fp)d_in[14];
    fp dec_w2 = (fp)d_in[15], dec_b2 = (fp)d_in[16];
    fp dec_w2_last = (fp)d_in[17], dec_b2_last = (fp)d_in[18];
    fp dec_gamma = (fp)d_in[19], dec_beta = (fp)d_in[20];

    const int* srcp = edge;            // edge_index[0]
    const int* dstp = edge + N_EDGES;  // edge_index[1]

    float* out_enc    = (float*)d_out;                       // [200000*32]
    float* out_dec    = (float*)d_out + (size_t)N_NODES * 32;        // [200000*128]
    float* out_global = (float*)d_out + (size_t)N_NODES * 160;       // [512*160]

    // workspace carve (256B aligned)
    char* p = (char*)d_ws;
    auto alloc = [&](size_t bytes) -> void* {
        void* r = (void*)p;
        p += (bytes + 255) & ~(size_t)255;
        return r;
    };
    int*   rowptr   = (int*)alloc((N_NODES + 1) * sizeof(int));
    int*   fillpos  = (int*)alloc(N_NODES * sizeof(int));
    int*   deg      = (int*)alloc(N_NODES * sizeof(int));
    int*   chunksum = (int*)alloc(128 * sizeof(int));
    int*   chunkoff = (int*)alloc(128 * sizeof(int));
    int*   gstart   = (int*)alloc((N_GRAPHS + 1) * sizeof(int));
    float* stats    = (float*)alloc(9 * 64 * sizeof(float));
    int*   csr      = (int*)alloc((size_t)N_EDGES * sizeof(int));
    float* hbuf     = (float*)alloc((size_t)N_NODES * 32 * sizeof(float));
    float* abuf     = (float*)alloc((size_t)N_NODES * 32 * sizeof(float));

    hipMemsetAsync(deg, 0, N_NODES * sizeof(int), stream);
    hipMemsetAsync(stats, 0, 9 * 64 * sizeof(float), stream);

    // CSR build
    k_hist<<<4096, 256, 0, stream>>>(dstp, deg);
    k_chunksum<<<NCHUNKS, 256, 0, stream>>>(deg, chunksum);
    k_scanchunks<<<1, 128, 0, stream>>>(chunksum, chunkoff, rowptr);
    k_scanfinal<<<NCHUNKS, 256, 0, stream>>>(deg, chunkoff, rowptr, fillpos);
    k_fill<<<4096, 256, 0, stream>>>(srcp, dstp, fillpos, csr);
    k_bounds<<<3, 256, 0, stream>>>(batch, gstart);

    // ---- Encoder layer 0 (128 -> 32) ----
    k_agg128<<<2500, 256, 0, stream>>>(x, rowptr, csr, e0_w1, e0_b1, e0_w2, e0_b2,
                                       abuf, stats);
    k_bn<<<4096, 256, 0, stream>>>(abuf, stats, enc_gamma, enc_beta, hbuf, nullptr);
    k_pool<<<N_GRAPHS, 256, 0, stream>>>(hbuf, gstart, out_global, 0);

    // ---- Encoder layers 1..4 (32 -> 32) ----
    for (int i = 0; i < 4; ++i) {
        float* st = stats + (1 + i) * 64;
        k_agg32<<<1250, 256, 0, stream>>>(hbuf, rowptr, csr,
                                          enc_w1 + i * 1024, enc_b1 + i * 32,
                                          enc_w2 + i * 1024, enc_b2 + i * 32,
                                          abuf, st);
        k_bn<<<4096, 256, 0, stream>>>(abuf, st,
                                       enc_gamma + (1 + i) * 32, enc_beta + (1 + i) * 32,
                                       hbuf, (i == 3) ? out_enc : nullptr);
        k_pool<<<N_GRAPHS, 256, 0, stream>>>(hbuf, gstart, out_global, (1 + i) * 32);
    }

    // ---- Decoder layers 0..3 (32 -> 32, BN) ----
    for (int i = 0; i < 4; ++i) {
        float* st = stats + (5 + i) * 64;
        k_agg32<<<1250, 256, 0, stream>>>(hbuf, rowptr, csr,
                                          dec_w1 + i * 1024, dec_b1 + i * 32,
                                          dec_w2 + i * 1024, dec_b2 + i * 32,
                                          abuf, st);
        k_bn<<<4096, 256, 0, stream>>>(abuf, st,
                                       dec_gamma + i * 32, dec_beta + i * 32,
                                       hbuf, nullptr);
    }

    // ---- Decoder layer 4 (32 -> 32 -> 128, relu, no BN) ----
    k_dec_last<<<2500, 256, 0, stream>>>(hbuf, rowptr, csr,
                                         dec_w1 + 4 * 1024, dec_b1 + 4 * 32,
                                         dec_w2_last, dec_b2_last, out_dec);
}

// Round 3
// 3450.515 us; speedup vs baseline: 1.9005x; 1.9005x over previous
//
#include <hip/hip_runtime.h>
#include <hip/hip_bf16.h>

#define N_NODES  200000
#define N_EDGES  6400000
#define N_GRAPHS 512
#define DIM_IN   128
#define HID      32
#define BN_EPS   1e-5f

// chunked scan params
#define CHUNK    2048
#define NCHUNKS  98   // ceil(200000/2048)

typedef const float* fp;

// ---------------- CSR build ----------------

__global__ void k_hist(const int* __restrict__ dst, int* __restrict__ deg) {
    int i = blockIdx.x * blockDim.x + threadIdx.x;
    int stride = gridDim.x * blockDim.x;
    for (; i < N_EDGES; i += stride) atomicAdd(&deg[dst[i]], 1);
}

__global__ void k_chunksum(const int* __restrict__ deg, int* __restrict__ chunksum) {
    __shared__ int red[256];
    int b = blockIdx.x, t = threadIdx.x;
    int base = b * CHUNK;
    int s = 0;
    for (int k = 0; k < 8; ++k) {
        int i = base + t + k * 256;
        if (i < N_NODES) s += deg[i];
    }
    red[t] = s; __syncthreads();
    for (int off = 128; off > 0; off >>= 1) {
        if (t < off) red[t] += red[t + off];
        __syncthreads();
    }
    if (t == 0) chunksum[b] = red[0];
}

__global__ void k_scanchunks(const int* __restrict__ chunksum, int* __restrict__ chunkoff,
                             int* __restrict__ rowptr) {
    __shared__ int buf[128];
    int t = threadIdx.x;  // 128 threads
    int v = (t < NCHUNKS) ? chunksum[t] : 0;
    buf[t] = v; __syncthreads();
    for (int off = 1; off < 128; off <<= 1) {
        int add = (t >= off) ? buf[t - off] : 0;
        __syncthreads();
        buf[t] += add;
        __syncthreads();
    }
    if (t < NCHUNKS) chunkoff[t] = buf[t] - v;  // exclusive
    if (t == 0) rowptr[N_NODES] = N_EDGES;      // every edge has valid dst
}

__global__ void k_scanfinal(const int* __restrict__ deg, const int* __restrict__ chunkoff,
                            int* __restrict__ rowptr, int* __restrict__ fillpos) {
    __shared__ int tsum[256];
    int b = blockIdx.x, t = threadIdx.x;
    int base = b * CHUNK + t * 8;
    int v[8]; int s = 0;
    for (int k = 0; k < 8; ++k) {
        int i = base + k;
        v[k] = (i < N_NODES) ? deg[i] : 0;
        s += v[k];
    }
    tsum[t] = s; __syncthreads();
    for (int off = 1; off < 256; off <<= 1) {
        int add = (t >= off) ? tsum[t - off] : 0;
        __syncthreads();
        tsum[t] += add;
        __syncthreads();
    }
    int run = tsum[t] - s + chunkoff[b];
    for (int k = 0; k < 8; ++k) {
        int i = base + k;
        if (i < N_NODES) { rowptr[i] = run; fillpos[i] = run; run += v[k]; }
    }
}

__global__ void k_fill(const int* __restrict__ src, const int* __restrict__ dst,
                       int* __restrict__ fillpos, int* __restrict__ csr) {
    int i = blockIdx.x * blockDim.x + threadIdx.x;
    int stride = gridDim.x * blockDim.x;
    for (; i < N_EDGES; i += stride) {
        int d = dst[i];
        int pos = atomicAdd(&fillpos[d], 1);
        csr[pos] = src[i];
    }
}

__global__ void k_bounds(const int* __restrict__ batch, int* __restrict__ gstart) {
    int g = blockIdx.x * blockDim.x + threadIdx.x;
    if (g > N_GRAPHS) return;
    if (g == N_GRAPHS) { gstart[g] = N_NODES; return; }
    int lo = 0, hi = N_NODES;
    while (lo < hi) {
        int mid = (lo + hi) >> 1;
        if (batch[mid] < g) lo = mid + 1; else hi = mid;
    }
    gstart[g] = lo;
}

// ---------------- Layer-0 pre-projection: y = x @ w1  (128 -> 32) ----------------

__global__ __launch_bounds__(256) void k_proj128(
    const float* __restrict__ x, fp w1, float* __restrict__ y)
{
    __shared__ float w1s[DIM_IN * 32];  // 16 KiB
    for (int i = threadIdx.x; i < DIM_IN * 32; i += 256) w1s[i] = w1[i];
    __syncthreads();
    const int lane = threadIdx.x & 63;
    const int c = lane & 31;
    const int srcBase = lane & 32;
    int worker   = (blockIdx.x * blockDim.x + threadIdx.x) >> 5;
    int nworkers = (gridDim.x * blockDim.x) >> 5;
    for (int n = worker; n < N_NODES; n += nworkers) {
        const float* xr = x + (size_t)n * DIM_IN;
        float x0 = xr[c], x1 = xr[32 + c], x2 = xr[64 + c], x3 = xr[96 + c];
        float acc = 0.f;
        #pragma unroll
        for (int k = 0; k < 32; ++k) {
            acc = fmaf(__shfl(x0, srcBase | k, 64), w1s[k * 32 + c], acc);
            acc = fmaf(__shfl(x1, srcBase | k, 64), w1s[(32 + k) * 32 + c], acc);
            acc = fmaf(__shfl(x2, srcBase | k, 64), w1s[(64 + k) * 32 + c], acc);
            acc = fmaf(__shfl(x3, srcBase | k, 64), w1s[(96 + k) * 32 + c], acc);
        }
        y[(size_t)n * 32 + c] = acc;
    }
}

// ---------------- Gather: s[n] = h[n] + sum_{j in N(n)} h[j]  (32-dim rows) ------
// Half-wave (32 lanes) per node; neighbor indices staged via one coalesced load
// + shfl broadcast; 8 independent 128B row loads in flight.

__global__ __launch_bounds__(256, 6) void k_gather(
    const float* __restrict__ h, const int* __restrict__ rowptr,
    const int* __restrict__ csr, float* __restrict__ sout)
{
    const int lane = threadIdx.x & 63;
    const int c = lane & 31;
    const int srcBase = lane & 32;
    int worker   = (blockIdx.x * blockDim.x + threadIdx.x) >> 5;
    int nworkers = (gridDim.x * blockDim.x) >> 5;
    for (int n = worker; n < N_NODES; n += nworkers) {
        int e0 = rowptr[n], e1 = rowptr[n + 1];
        float acc = h[(size_t)n * 32 + c];
        int e = e0;
        while (e < e1) {
            int rem = e1 - e;
            int cnt = rem < 32 ? rem : 32;
            int myidx = (c < cnt) ? csr[e + c] : 0;
            int k = 0;
            for (; k + 8 <= cnt; k += 8) {
                int i0 = __shfl(myidx, srcBase | (k + 0), 64);
                int i1 = __shfl(myidx, srcBase | (k + 1), 64);
                int i2 = __shfl(myidx, srcBase | (k + 2), 64);
                int i3 = __shfl(myidx, srcBase | (k + 3), 64);
                int i4 = __shfl(myidx, srcBase | (k + 4), 64);
                int i5 = __shfl(myidx, srcBase | (k + 5), 64);
                int i6 = __shfl(myidx, srcBase | (k + 6), 64);
                int i7 = __shfl(myidx, srcBase | (k + 7), 64);
                float v0 = h[(size_t)i0 * 32 + c];
                float v1 = h[(size_t)i1 * 32 + c];
                float v2 = h[(size_t)i2 * 32 + c];
                float v3 = h[(size_t)i3 * 32 + c];
                float v4 = h[(size_t)i4 * 32 + c];
                float v5 = h[(size_t)i5 * 32 + c];
                float v6 = h[(size_t)i6 * 32 + c];
                float v7 = h[(size_t)i7 * 32 + c];
                acc += ((v0 + v1) + (v2 + v3)) + ((v4 + v5) + (v6 + v7));
            }
            for (; k < cnt; ++k) {
                int s = __shfl(myidx, srcBase | k, 64);
                acc += h[(size_t)s * 32 + c];
            }
            e += cnt;
        }
        sout[(size_t)n * 32 + c] = acc;
    }
}

// ---------------- MLP kernels (streaming, fused BN-stats) ----------------

// generic 32->32->32: a = relu(relu(s@w1+b1)@w2+b2), in-place on s, stats out.
__global__ __launch_bounds__(256) void k_mlp32(
    float* __restrict__ s, fp w1, fp b1, fp w2, fp b2, float* __restrict__ stats)
{
    const int lane = threadIdx.x & 63;
    const int c = lane & 31;
    const int srcBase = lane & 32;
    float w1r[32], w2r[32];
    #pragma unroll
    for (int k = 0; k < 32; ++k) {
        w1r[k] = w1[k * 32 + c];
        w2r[k] = w2[k * 32 + c];
    }
    const float b1c = b1[c];
    const float b2c = b2[c];
    int worker   = (blockIdx.x * blockDim.x + threadIdx.x) >> 5;
    int nworkers = (gridDim.x * blockDim.x) >> 5;
    float s1 = 0.f, s2 = 0.f;
    for (int n = worker; n < N_NODES; n += nworkers) {
        float sv = s[(size_t)n * 32 + c];
        float acc1 = b1c;
        #pragma unroll
        for (int k = 0; k < 32; ++k)
            acc1 = fmaf(__shfl(sv, srcBase | k, 64), w1r[k], acc1);
        float h3 = fmaxf(acc1, 0.f);
        float acc2 = b2c;
        #pragma unroll
        for (int k = 0; k < 32; ++k)
            acc2 = fmaf(__shfl(h3, srcBase | k, 64), w2r[k], acc2);
        float a = fmaxf(acc2, 0.f);
        s[(size_t)n * 32 + c] = a;
        s1 += a; s2 += a * a;
    }
    s1 += __shfl_xor(s1, 32, 64);
    s2 += __shfl_xor(s2, 32, 64);
    __shared__ float ls1[4][32], ls2[4][32];
    int w = threadIdx.x >> 6;
    if ((threadIdx.x & 32) == 0) { ls1[w][c] = s1; ls2[w][c] = s2; }
    __syncthreads();
    if (threadIdx.x < 32) {
        float t1 = ls1[0][c] + ls1[1][c] + ls1[2][c] + ls1[3][c];
        float t2 = ls2[0][c] + ls2[1][c] + ls2[2][c] + ls2[3][c];
        atomicAdd(&stats[c], t1);
        atomicAdd(&stats[32 + c], t2);
    }
}

// layer-0 variant: s already = (x+agg)@w1, so stage 1 is elementwise.
__global__ __launch_bounds__(256) void k_mlp0(
    float* __restrict__ s, fp b1, fp w2, fp b2, float* __restrict__ stats)
{
    const int lane = threadIdx.x & 63;
    const int c = lane & 31;
    const int srcBase = lane & 32;
    float w2r[32];
    #pragma unroll
    for (int k = 0; k < 32; ++k) w2r[k] = w2[k * 32 + c];
    const float b1c = b1[c];
    const float b2c = b2[c];
    int worker   = (blockIdx.x * blockDim.x + threadIdx.x) >> 5;
    int nworkers = (gridDim.x * blockDim.x) >> 5;
    float s1 = 0.f, s2 = 0.f;
    for (int n = worker; n < N_NODES; n += nworkers) {
        float sv = s[(size_t)n * 32 + c];
        float h3 = fmaxf(sv + b1c, 0.f);
        float acc2 = b2c;
        #pragma unroll
        for (int k = 0; k < 32; ++k)
            acc2 = fmaf(__shfl(h3, srcBase | k, 64), w2r[k], acc2);
        float a = fmaxf(acc2, 0.f);
        s[(size_t)n * 32 + c] = a;
        s1 += a; s2 += a * a;
    }
    s1 += __shfl_xor(s1, 32, 64);
    s2 += __shfl_xor(s2, 32, 64);
    __shared__ float ls1[4][32], ls2[4][32];
    int w = threadIdx.x >> 6;
    if ((threadIdx.x & 32) == 0) { ls1[w][c] = s1; ls2[w][c] = s2; }
    __syncthreads();
    if (threadIdx.x < 32) {
        float t1 = ls1[0][c] + ls1[1][c] + ls1[2][c] + ls1[3][c];
        float t2 = ls2[0][c] + ls2[1][c] + ls2[2][c] + ls2[3][c];
        atomicAdd(&stats[c], t1);
        atomicAdd(&stats[32 + c], t2);
    }
}

// decoder last: out = relu(relu(s@w1+b1)@w2_last+b2_last), 32 -> 32 -> 128.
__global__ __launch_bounds__(256) void k_mlp_last(
    const float* __restrict__ s, fp w1, fp b1, fp w2 /*[32][128]*/, fp b2,
    float* __restrict__ out)
{
    const int lane = threadIdx.x & 63;
    const int c = lane & 31;
    float w1r[32], w2a[32], w2b[32];
    #pragma unroll
    for (int k = 0; k < 32; ++k) {
        w1r[k] = w1[k * 32 + c];
        w2a[k] = w2[k * 128 + 2 * lane];
        w2b[k] = w2[k * 128 + 2 * lane + 1];
    }
    const float b1c = b1[c];
    const float b2a = b2[2 * lane];
    const float b2b = b2[2 * lane + 1];
    int worker   = (blockIdx.x * blockDim.x + threadIdx.x) >> 6;
    int nworkers = (gridDim.x * blockDim.x) >> 6;
    for (int n = worker; n < N_NODES; n += nworkers) {
        float sv = s[(size_t)n * 32 + c];  // duplicated across halves
        float acc1 = b1c;
        #pragma unroll
        for (int k = 0; k < 32; ++k)
            acc1 = fmaf(__shfl(sv, k, 64), w1r[k], acc1);
        float h3 = fmaxf(acc1, 0.f);
        float oa = b2a, ob = b2b;
        #pragma unroll
        for (int k = 0; k < 32; ++k) {
            float v = __shfl(h3, (lane & 32) | k, 64);
            oa = fmaf(v, w2a[k], oa);
            ob = fmaf(v, w2b[k], ob);
        }
        oa = fmaxf(oa, 0.f); ob = fmaxf(ob, 0.f);
        float2 pr; pr.x = oa; pr.y = ob;
        reinterpret_cast<float2*>(out)[(size_t)n * 64 + lane] = pr;
    }
}

// BatchNorm apply: hout = gamma*(a-m)/sqrt(v+eps)+beta; optional fp32 mirror to d_out.
__global__ void k_bn(const float* __restrict__ a, const float* __restrict__ stats,
                     fp gamma, fp beta, float* __restrict__ hout,
                     float* __restrict__ out_mirror)
{
    const int c = threadIdx.x & 31;
    float m  = stats[c] * (1.f / N_NODES);
    float vv = stats[32 + c] * (1.f / N_NODES) - m * m;
    float sc = gamma[c] / sqrtf(vv + BN_EPS);
    float sh = beta[c] - m * sc;
    int i = blockIdx.x * blockDim.x + threadIdx.x;
    int stride = gridDim.x * blockDim.x;  // multiple of 32 -> (i&31)==c always
    for (; i < N_NODES * 32; i += stride) {
        float val = fmaf(a[i], sc, sh);
        hout[i] = val;
        if (out_mirror) out_mirror[i] = val;
    }
}

// Global add-pool of one encoder layer into d_out global_rep slice (batch sorted).
__global__ void k_pool(const float* __restrict__ h, const int* __restrict__ gstart,
                       float* __restrict__ out, int col0)
{
    int g = blockIdx.x;
    int t = threadIdx.x;
    int f = t & 31, j = t >> 5;  // 8 node-groups x 32 features
    int n0 = gstart[g], n1 = gstart[g + 1];
    float s = 0.f;
    for (int n = n0 + j; n < n1; n += 8) s += h[(size_t)n * 32 + f];
    __shared__ float red[8][32];
    red[j][f] = s; __syncthreads();
    if (t < 32) {
        float tot = 0.f;
        #pragma unroll
        for (int k = 0; k < 8; ++k) tot += red[k][f];
        out[g * (5 * HID) + col0 + f] = tot;
    }
}

// ---------------- launch ----------------

extern "C" void kernel_launch(void* const* d_in, const int* in_sizes, int n_in,
                              void* d_out, int out_size, void* d_ws, size_t ws_size,
                              hipStream_t stream) {
    fp         x        = (fp)d_in[0];
    const int* edge     = (const int*)d_in[1];
    const int* batch    = (const int*)d_in[2];
    fp e0_w1 = (fp)d_in[3],  e0_b1 = (fp)d_in[4];
    fp e0_w2 = (fp)d_in[5],  e0_b2 = (fp)d_in[6];
    fp enc_w1 = (fp)d_in[7],  enc_b1 = (fp)d_in[8];
    fp enc_w2 = (fp)d_in[9],  enc_b2 = (fp)d_in[10];
    fp enc_gamma = (fp)d_in[11], enc_beta = (fp)d_in[12];
    fp dec_w1 = (fp)d_in[13], dec_b1 = (fp)d_in[14];
    fp dec_w2 = (fp)d_in[15], dec_b2 = (fp)d_in[16];
    fp dec_w2_last = (fp)d_in[17], dec_b2_last = (fp)d_in[18];
    fp dec_gamma = (fp)d_in[19], dec_beta = (fp)d_in[20];

    const int* srcp = edge;            // edge_index[0]
    const int* dstp = edge + N_EDGES;  // edge_index[1]

    float* out_enc    = (float*)d_out;                            // [200000*32]
    float* out_dec    = (float*)d_out + (size_t)N_NODES * 32;     // [200000*128]
    float* out_global = (float*)d_out + (size_t)N_NODES * 160;    // [512*160]

    // workspace carve (256B aligned)
    char* p = (char*)d_ws;
    auto alloc = [&](size_t bytes) -> void* {
        void* r = (void*)p;
        p += (bytes + 255) & ~(size_t)255;
        return r;
    };
    int*   rowptr   = (int*)alloc((N_NODES + 1) * sizeof(int));
    int*   fillpos  = (int*)alloc(N_NODES * sizeof(int));
    int*   deg      = (int*)alloc(N_NODES * sizeof(int));
    int*   chunksum = (int*)alloc(128 * sizeof(int));
    int*   chunkoff = (int*)alloc(128 * sizeof(int));
    int*   gstart   = (int*)alloc((N_GRAPHS + 1) * sizeof(int));
    float* stats    = (float*)alloc(9 * 64 * sizeof(float));
    int*   csr      = (int*)alloc((size_t)N_EDGES * sizeof(int));
    float* hbuf     = (float*)alloc((size_t)N_NODES * 32 * sizeof(float));
    float* sbuf     = (float*)alloc((size_t)N_NODES * 32 * sizeof(float));

    hipMemsetAsync(deg, 0, N_NODES * sizeof(int), stream);
    hipMemsetAsync(stats, 0, 9 * 64 * sizeof(float), stream);

    // CSR build
    k_hist<<<4096, 256, 0, stream>>>(dstp, deg);
    k_chunksum<<<NCHUNKS, 256, 0, stream>>>(deg, chunksum);
    k_scanchunks<<<1, 128, 0, stream>>>(chunksum, chunkoff, rowptr);
    k_scanfinal<<<NCHUNKS, 256, 0, stream>>>(deg, chunkoff, rowptr, fillpos);
    k_fill<<<4096, 256, 0, stream>>>(srcp, dstp, fillpos, csr);
    k_bounds<<<3, 256, 0, stream>>>(batch, gstart);

    // ---- Encoder layer 0 (pre-projected) ----
    k_proj128<<<1024, 256, 0, stream>>>(x, e0_w1, hbuf);   // hbuf = y = x@w1
    k_gather<<<2048, 256, 0, stream>>>(hbuf, rowptr, csr, sbuf);
    k_mlp0<<<1024, 256, 0, stream>>>(sbuf, e0_b1, e0_w2, e0_b2, stats);
    k_bn<<<4096, 256, 0, stream>>>(sbuf, stats, enc_gamma, enc_beta, hbuf, nullptr);
    k_pool<<<N_GRAPHS, 256, 0, stream>>>(hbuf, gstart, out_global, 0);

    // ---- Encoder layers 1..4 (32 -> 32) ----
    for (int i = 0; i < 4; ++i) {
        float* st = stats + (1 + i) * 64;
        k_gather<<<2048, 256, 0, stream>>>(hbuf, rowptr, csr, sbuf);
        k_mlp32<<<1024, 256, 0, stream>>>(sbuf,
                                          enc_w1 + i * 1024, enc_b1 + i * 32,
                                          enc_w2 + i * 1024, enc_b2 + i * 32, st);
        k_bn<<<4096, 256, 0, stream>>>(sbuf, st,
                                       enc_gamma + (1 + i) * 32, enc_beta + (1 + i) * 32,
                                       hbuf, (i == 3) ? out_enc : nullptr);
        k_pool<<<N_GRAPHS, 256, 0, stream>>>(hbuf, gstart, out_global, (1 + i) * 32);
    }

    // ---- Decoder layers 0..3 (32 -> 32, BN) ----
    for (int i = 0; i < 4; ++i) {
        float* st = stats + (5 + i) * 64;
        k_gather<<<2048, 256, 0, stream>>>(hbuf, rowptr, csr, sbuf);
        k_mlp32<<<1024, 256, 0, stream>>>(sbuf,
                                          dec_w1 + i * 1024, dec_b1 + i * 32,
                                          dec_w2 + i * 1024, dec_b2 + i * 32, st);
        k_bn<<<4096, 256, 0, stream>>>(sbuf, st,
                                       dec_gamma + i * 32, dec_beta + i * 32,
                                       hbuf, nullptr);
    }

    // ---- Decoder layer 4 (32 -> 32 -> 128, relu, no BN) ----
    k_gather<<<2048, 256, 0, stream>>>(hbuf, rowptr, csr, sbuf);
    k_mlp_last<<<1024, 256, 0, stream>>>(sbuf,
                                         dec_w1 + 4 * 1024, dec_b1 + 4 * 32,
                                         dec_w2_last, dec_b2_last, out_dec);
}

// Round 5
// 2999.760 us; speedup vs baseline: 2.1861x; 1.1503x over previous
//
#include <hip/hip_runtime.h>
#include <hip/hip_bf16.h>
#include <hip/hip_fp16.h>
#include <string.h>

#define N_NODES  200000
#define N_EDGES  6400000
#define N_GRAPHS 512
#define DIM_IN   128
#define HID      32
#define BN_EPS   1e-5f

// chunked scan params
#define CHUNK    2048
#define NCHUNKS  98   // ceil(200000/2048)

typedef const float* fp;

// fp16 storage helpers (RNE via v_cvt_f16_f32 / v_cvt_f32_f16)
__device__ __forceinline__ unsigned short f2h(float f) {
    __half h = __float2half(f);
    unsigned short u; __builtin_memcpy(&u, &h, 2); return u;
}
__device__ __forceinline__ float2 h2f2(unsigned int u) {
    __half2 h; __builtin_memcpy(&h, &u, 4);
    return __half22float2(h);
}

// ---------------- CSR build ----------------

// LDS-binned histogram: 16 node-ranges of 12500 (50KB LDS each), 16 blocks/range.
__global__ __launch_bounds__(256) void k_hist2(const int* __restrict__ dst,
                                               int* __restrict__ deg) {
    __shared__ int lh[12500];  // 50 KB
    const int grp = blockIdx.x & 15;        // node range
    const int blk = blockIdx.x >> 4;        // edge slice [0,16)
    const int lo = grp * 12500;
    for (int j = threadIdx.x; j < 12500; j += 256) lh[j] = 0;
    __syncthreads();
    const int4* d4 = reinterpret_cast<const int4*>(dst) + blk * 100000;
    for (int j = threadIdx.x; j < 100000; j += 256) {
        int4 v = d4[j];
        int a;
        a = v.x - lo; if ((unsigned)a < 12500u) atomicAdd(&lh[a], 1);
        a = v.y - lo; if ((unsigned)a < 12500u) atomicAdd(&lh[a], 1);
        a = v.z - lo; if ((unsigned)a < 12500u) atomicAdd(&lh[a], 1);
        a = v.w - lo; if ((unsigned)a < 12500u) atomicAdd(&lh[a], 1);
    }
    __syncthreads();
    for (int j = threadIdx.x; j < 12500; j += 256) {
        int c = lh[j];
        if (c) atomicAdd(&deg[lo + j], c);
    }
}

__global__ void k_chunksum(const int* __restrict__ deg, int* __restrict__ chunksum) {
    __shared__ int red[256];
    int b = blockIdx.x, t = threadIdx.x;
    int base = b * CHUNK;
    int s = 0;
    for (int k = 0; k < 8; ++k) {
        int i = base + t + k * 256;
        if (i < N_NODES) s += deg[i];
    }
    red[t] = s; __syncthreads();
    for (int off = 128; off > 0; off >>= 1) {
        if (t < off) red[t] += red[t + off];
        __syncthreads();
    }
    if (t == 0) chunksum[b] = red[0];
}

__global__ void k_scanchunks(const int* __restrict__ chunksum, int* __restrict__ chunkoff,
                             int* __restrict__ rowptr) {
    __shared__ int buf[128];
    int t = threadIdx.x;  // 128 threads
    int v = (t < NCHUNKS) ? chunksum[t] : 0;
    buf[t] = v; __syncthreads();
    for (int off = 1; off < 128; off <<= 1) {
        int add = (t >= off) ? buf[t - off] : 0;
        __syncthreads();
        buf[t] += add;
        __syncthreads();
    }
    if (t < NCHUNKS) chunkoff[t] = buf[t] - v;  // exclusive
    if (t == 0) rowptr[N_NODES] = N_EDGES;      // every edge has valid dst
}

__global__ void k_scanfinal(const int* __restrict__ deg, const int* __restrict__ chunkoff,
                            int* __restrict__ rowptr, int* __restrict__ fillpos) {
    __shared__ int tsum[256];
    int b = blockIdx.x, t = threadIdx.x;
    int base = b * CHUNK + t * 8;
    int v[8]; int s = 0;
    for (int k = 0; k < 8; ++k) {
        int i = base + k;
        v[k] = (i < N_NODES) ? deg[i] : 0;
        s += v[k];
    }
    tsum[t] = s; __syncthreads();
    for (int off = 1; off < 256; off <<= 1) {
        int add = (t >= off) ? tsum[t - off] : 0;
        __syncthreads();
        tsum[t] += add;
        __syncthreads();
    }
    int run = tsum[t] - s + chunkoff[b];
    for (int k = 0; k < 8; ++k) {
        int i = base + k;
        if (i < N_NODES) { rowptr[i] = run; fillpos[i] = run; run += v[k]; }
    }
}

// Ranged fill: group = blockIdx&7 (XCD round-robin) handles dst in [g*25000,(g+1)*25000);
// csr writes land in a ~3.2MB window that fits the group's XCD L2.
__global__ __launch_bounds__(256) void k_fill2(
    const int* __restrict__ src, const int* __restrict__ dst,
    int* __restrict__ fillpos, int* __restrict__ csr)
{
    const int grp = blockIdx.x & 7;
    const int blk = blockIdx.x >> 3;   // [0,128)
    const int lo = grp * 25000, hi = lo + 25000;
    const int4* d4 = reinterpret_cast<const int4*>(dst) + blk * 12500;
    const int4* s4 = reinterpret_cast<const int4*>(src) + blk * 12500;
    for (int j = threadIdx.x; j < 12500; j += 256) {
        int4 d = d4[j];
        int4 s = s4[j];
        if (d.x >= lo && d.x < hi) { int p = atomicAdd(&fillpos[d.x], 1); csr[p] = s.x; }
        if (d.y >= lo && d.y < hi) { int p = atomicAdd(&fillpos[d.y], 1); csr[p] = s.y; }
        if (d.z >= lo && d.z < hi) { int p = atomicAdd(&fillpos[d.z], 1); csr[p] = s.z; }
        if (d.w >= lo && d.w < hi) { int p = atomicAdd(&fillpos[d.w], 1); csr[p] = s.w; }
    }
}

__global__ void k_bounds(const int* __restrict__ batch, int* __restrict__ gstart) {
    int g = blockIdx.x * blockDim.x + threadIdx.x;
    if (g > N_GRAPHS) return;
    if (g == N_GRAPHS) { gstart[g] = N_NODES; return; }
    int lo = 0, hi = N_NODES;
    while (lo < hi) {
        int mid = (lo + hi) >> 1;
        if (batch[mid] < g) lo = mid + 1; else hi = mid;
    }
    gstart[g] = lo;
}

// ---------------- Layer-0 pre-projection: y = x @ w1  (128 -> 32) ----------------

__global__ __launch_bounds__(256) void k_proj128(
    const float* __restrict__ x, fp w1, float* __restrict__ y,
    unsigned short* __restrict__ y16)
{
    __shared__ float w1s[DIM_IN * 32];  // 16 KiB
    for (int i = threadIdx.x; i < DIM_IN * 32; i += 256) w1s[i] = w1[i];
    __syncthreads();
    const int lane = threadIdx.x & 63;
    const int c = lane & 31;
    const int srcBase = lane & 32;
    int worker   = (blockIdx.x * blockDim.x + threadIdx.x) >> 5;
    int nworkers = (gridDim.x * blockDim.x) >> 5;
    for (int n = worker; n < N_NODES; n += nworkers) {
        const float* xr = x + (size_t)n * DIM_IN;
        float x0 = xr[c], x1 = xr[32 + c], x2 = xr[64 + c], x3 = xr[96 + c];
        float acc = 0.f;
        #pragma unroll
        for (int k = 0; k < 32; ++k) {
            acc = fmaf(__shfl(x0, srcBase | k, 64), w1s[k * 32 + c], acc);
            acc = fmaf(__shfl(x1, srcBase | k, 64), w1s[(32 + k) * 32 + c], acc);
            acc = fmaf(__shfl(x2, srcBase | k, 64), w1s[(64 + k) * 32 + c], acc);
            acc = fmaf(__shfl(x3, srcBase | k, 64), w1s[(96 + k) * 32 + c], acc);
        }
        y[(size_t)n * 32 + c] = acc;
        y16[(size_t)n * 32 + c] = f2h(acc);
    }
}

// ---------------- Gather: s[n] = h[n] + sum_{j in N(n)} h16[j] ----------------
// Quarter-wave (16 lanes, 2 features/lane) per node; neighbor rows fp16 (64B).

__global__ __launch_bounds__(256) void k_gather16(
    const float* __restrict__ h, const unsigned short* __restrict__ h16,
    const int* __restrict__ rowptr, const int* __restrict__ csr,
    float* __restrict__ sout)
{
    const int lane = threadIdx.x & 63;
    const int sub = lane & 15;
    const int srcBase = lane & 48;
    const unsigned int* hp = reinterpret_cast<const unsigned int*>(h16);  // half2
    const float2* hs = reinterpret_cast<const float2*>(h);
    float2* so = reinterpret_cast<float2*>(sout);
    int worker   = (blockIdx.x * blockDim.x + threadIdx.x) >> 4;
    int nworkers = (gridDim.x * blockDim.x) >> 4;
    for (int n = worker; n < N_NODES; n += nworkers) {
        int e0 = rowptr[n], e1 = rowptr[n + 1];
        float2 self = hs[(size_t)n * 16 + sub];
        float a0 = self.x, a1 = self.y;
        int e = e0;
        while (e < e1) {
            int rem = e1 - e;
            int cnt = rem < 16 ? rem : 16;
            int myidx = (sub < cnt) ? csr[e + sub] : 0;
            int k = 0;
            for (; k + 8 <= cnt; k += 8) {
                int i0 = __shfl(myidx, srcBase | (k + 0), 64);
                int i1 = __shfl(myidx, srcBase | (k + 1), 64);
                int i2 = __shfl(myidx, srcBase | (k + 2), 64);
                int i3 = __shfl(myidx, srcBase | (k + 3), 64);
                int i4 = __shfl(myidx, srcBase | (k + 4), 64);
                int i5 = __shfl(myidx, srcBase | (k + 5), 64);
                int i6 = __shfl(myidx, srcBase | (k + 6), 64);
                int i7 = __shfl(myidx, srcBase | (k + 7), 64);
                unsigned int u0 = hp[(size_t)i0 * 16 + sub];
                unsigned int u1 = hp[(size_t)i1 * 16 + sub];
                unsigned int u2 = hp[(size_t)i2 * 16 + sub];
                unsigned int u3 = hp[(size_t)i3 * 16 + sub];
                unsigned int u4 = hp[(size_t)i4 * 16 + sub];
                unsigned int u5 = hp[(size_t)i5 * 16 + sub];
                unsigned int u6 = hp[(size_t)i6 * 16 + sub];
                unsigned int u7 = hp[(size_t)i7 * 16 + sub];
                float2 f0 = h2f2(u0), f1 = h2f2(u1), f2 = h2f2(u2), f3 = h2f2(u3);
                float2 f4 = h2f2(u4), f5 = h2f2(u5), f6 = h2f2(u6), f7 = h2f2(u7);
                a0 += ((f0.x + f1.x) + (f2.x + f3.x)) + ((f4.x + f5.x) + (f6.x + f7.x));
                a1 += ((f0.y + f1.y) + (f2.y + f3.y)) + ((f4.y + f5.y) + (f6.y + f7.y));
            }
            for (; k < cnt; ++k) {
                int s = __shfl(myidx, srcBase | k, 64);
                float2 f = h2f2(hp[(size_t)s * 16 + sub]);
                a0 += f.x; a1 += f.y;
            }
            e += cnt;
        }
        float2 o; o.x = a0; o.y = a1;
        so[(size_t)n * 16 + sub] = o;
    }
}

// ---------------- MLP kernels (streaming, fused BN-stats) ----------------

__global__ __launch_bounds__(256) void k_mlp32(
    float* __restrict__ s, fp w1, fp b1, fp w2, fp b2, float* __restrict__ stats)
{
    const int lane = threadIdx.x & 63;
    const int c = lane & 31;
    const int srcBase = lane & 32;
    float w1r[32], w2r[32];
    #pragma unroll
    for (int k = 0; k < 32; ++k) {
        w1r[k] = w1[k * 32 + c];
        w2r[k] = w2[k * 32 + c];
    }
    const float b1c = b1[c];
    const float b2c = b2[c];
    int worker   = (blockIdx.x * blockDim.x + threadIdx.x) >> 5;
    int nworkers = (gridDim.x * blockDim.x) >> 5;
    float s1 = 0.f, s2 = 0.f;
    for (int n = worker; n < N_NODES; n += nworkers) {
        float sv = s[(size_t)n * 32 + c];
        float acc1 = b1c;
        #pragma unroll
        for (int k = 0; k < 32; ++k)
            acc1 = fmaf(__shfl(sv, srcBase | k, 64), w1r[k], acc1);
        float h3 = fmaxf(acc1, 0.f);
        float acc2 = b2c;
        #pragma unroll
        for (int k = 0; k < 32; ++k)
            acc2 = fmaf(__shfl(h3, srcBase | k, 64), w2r[k], acc2);
        float a = fmaxf(acc2, 0.f);
        s[(size_t)n * 32 + c] = a;
        s1 += a; s2 += a * a;
    }
    s1 += __shfl_xor(s1, 32, 64);
    s2 += __shfl_xor(s2, 32, 64);
    __shared__ float ls1[4][32], ls2[4][32];
    int w = threadIdx.x >> 6;
    if ((threadIdx.x & 32) == 0) { ls1[w][c] = s1; ls2[w][c] = s2; }
    __syncthreads();
    if (threadIdx.x < 32) {
        float t1 = ls1[0][c] + ls1[1][c] + ls1[2][c] + ls1[3][c];
        float t2 = ls2[0][c] + ls2[1][c] + ls2[2][c] + ls2[3][c];
        atomicAdd(&stats[c], t1);
        atomicAdd(&stats[32 + c], t2);
    }
}

// layer-0 variant: s already = (x+agg)@w1, so stage 1 is elementwise.
__global__ __launch_bounds__(256) void k_mlp0(
    float* __restrict__ s, fp b1, fp w2, fp b2, float* __restrict__ stats)
{
    const int lane = threadIdx.x & 63;
    const int c = lane & 31;
    const int srcBase = lane & 32;
    float w2r[32];
    #pragma unroll
    for (int k = 0; k < 32; ++k) w2r[k] = w2[k * 32 + c];
    const float b1c = b1[c];
    const float b2c = b2[c];
    int worker   = (blockIdx.x * blockDim.x + threadIdx.x) >> 5;
    int nworkers = (gridDim.x * blockDim.x) >> 5;
    float s1 = 0.f, s2 = 0.f;
    for (int n = worker; n < N_NODES; n += nworkers) {
        float sv = s[(size_t)n * 32 + c];
        float h3 = fmaxf(sv + b1c, 0.f);
        float acc2 = b2c;
        #pragma unroll
        for (int k = 0; k < 32; ++k)
            acc2 = fmaf(__shfl(h3, srcBase | k, 64), w2r[k], acc2);
        float a = fmaxf(acc2, 0.f);
        s[(size_t)n * 32 + c] = a;
        s1 += a; s2 += a * a;
    }
    s1 += __shfl_xor(s1, 32, 64);
    s2 += __shfl_xor(s2, 32, 64);
    __shared__ float ls1[4][32], ls2[4][32];
    int w = threadIdx.x >> 6;
    if ((threadIdx.x & 32) == 0) { ls1[w][c] = s1; ls2[w][c] = s2; }
    __syncthreads();
    if (threadIdx.x < 32) {
        float t1 = ls1[0][c] + ls1[1][c] + ls1[2][c] + ls1[3][c];
        float t2 = ls2[0][c] + ls2[1][c] + ls2[2][c] + ls2[3][c];
        atomicAdd(&stats[c], t1);
        atomicAdd(&stats[32 + c], t2);
    }
}

// decoder last: out = relu(relu(s@w1+b1)@w2_last+b2_last), 32 -> 32 -> 128.
__global__ __launch_bounds__(256) void k_mlp_last(
    const float* __restrict__ s, fp w1, fp b1, fp w2 /*[32][128]*/, fp b2,
    float* __restrict__ out)
{
    const int lane = threadIdx.x & 63;
    const int c = lane & 31;
    float w1r[32], w2a[32], w2b[32];
    #pragma unroll
    for (int k = 0; k < 32; ++k) {
        w1r[k] = w1[k * 32 + c];
        w2a[k] = w2[k * 128 + 2 * lane];
        w2b[k] = w2[k * 128 + 2 * lane + 1];
    }
    const float b1c = b1[c];
    const float b2a = b2[2 * lane];
    const float b2b = b2[2 * lane + 1];
    int worker   = (blockIdx.x * blockDim.x + threadIdx.x) >> 6;
    int nworkers = (gridDim.x * blockDim.x) >> 6;
    for (int n = worker; n < N_NODES; n += nworkers) {
        float sv = s[(size_t)n * 32 + c];  // duplicated across halves
        float acc1 = b1c;
        #pragma unroll
        for (int k = 0; k < 32; ++k)
            acc1 = fmaf(__shfl(sv, k, 64), w1r[k], acc1);
        float h3 = fmaxf(acc1, 0.f);
        float oa = b2a, ob = b2b;
        #pragma unroll
        for (int k = 0; k < 32; ++k) {
            float v = __shfl(h3, (lane & 32) | k, 64);
            oa = fmaf(v, w2a[k], oa);
            ob = fmaf(v, w2b[k], ob);
        }
        oa = fmaxf(oa, 0.f); ob = fmaxf(ob, 0.f);
        float2 pr; pr.x = oa; pr.y = ob;
        reinterpret_cast<float2*>(out)[(size_t)n * 64 + lane] = pr;
    }
}

// BatchNorm apply: fp32 hout + fp16 h16out (+ optional fp32 mirror to d_out).
__global__ void k_bn(const float* __restrict__ a, const float* __restrict__ stats,
                     fp gamma, fp beta, float* __restrict__ hout,
                     unsigned short* __restrict__ h16out,
                     float* __restrict__ out_mirror)
{
    const int c = threadIdx.x & 31;
    float m  = stats[c] * (1.f / N_NODES);
    float vv = stats[32 + c] * (1.f / N_NODES) - m * m;
    float sc = gamma[c] / sqrtf(vv + BN_EPS);
    float sh = beta[c] - m * sc;
    int i = blockIdx.x * blockDim.x + threadIdx.x;
    int stride = gridDim.x * blockDim.x;  // multiple of 32 -> (i&31)==c always
    for (; i < N_NODES * 32; i += stride) {
        float val = fmaf(a[i], sc, sh);
        hout[i] = val;
        h16out[i] = f2h(val);
        if (out_mirror) out_mirror[i] = val;
    }
}

// Global add-pool of one encoder layer into d_out global_rep slice (batch sorted).
__global__ void k_pool(const float* __restrict__ h, const int* __restrict__ gstart,
                       float* __restrict__ out, int col0)
{
    int g = blockIdx.x;
    int t = threadIdx.x;
    int f = t & 31, j = t >> 5;  // 8 node-groups x 32 features
    int n0 = gstart[g], n1 = gstart[g + 1];
    float s = 0.f;
    for (int n = n0 + j; n < n1; n += 8) s += h[(size_t)n * 32 + f];
    __shared__ float red[8][32];
    red[j][f] = s; __syncthreads();
    if (t < 32) {
        float tot = 0.f;
        #pragma unroll
        for (int k = 0; k < 8; ++k) tot += red[k][f];
        out[g * (5 * HID) + col0 + f] = tot;
    }
}

// ---------------- launch ----------------

extern "C" void kernel_launch(void* const* d_in, const int* in_sizes, int n_in,
                              void* d_out, int out_size, void* d_ws, size_t ws_size,
                              hipStream_t stream) {
    fp         x        = (fp)d_in[0];
    const int* edge     = (const int*)d_in[1];
    const int* batch    = (const int*)d_in[2];
    fp e0_w1 = (fp)d_in[3],  e0_b1 = (fp)d_in[4];
    fp e0_w2 = (fp)d_in[5],  e0_b2 = (fp)d_in[6];
    fp enc_w1 = (fp)d_in[7],  enc_b1 = (fp)d_in[8];
    fp enc_w2 = (fp)d_in[9],  enc_b2 = (fp)d_in[10];
    fp enc_gamma = (fp)d_in[11], enc_beta = (fp)d_in[12];
    fp dec_w1 = (fp)d_in[13], dec_b1 = (fp)d_in[14];
    fp dec_w2 = (fp)d_in[15], dec_b2 = (fp)d_in[16];
    fp dec_w2_last = (fp)d_in[17], dec_b2_last = (fp)d_in[18];
    fp dec_gamma = (fp)d_in[19], dec_beta = (fp)d_in[20];

    const int* srcp = edge;            // edge_index[0]
    const int* dstp = edge + N_EDGES;  // edge_index[1]

    float* out_enc    = (float*)d_out;                            // [200000*32]
    float* out_dec    = (float*)d_out + (size_t)N_NODES * 32;     // [200000*128]
    float* out_global = (float*)d_out + (size_t)N_NODES * 160;    // [512*160]

    // workspace carve (256B aligned)
    char* p = (char*)d_ws;
    auto alloc = [&](size_t bytes) -> void* {
        void* r = (void*)p;
        p += (bytes + 255) & ~(size_t)255;
        return r;
    };
    int*   rowptr   = (int*)alloc((N_NODES + 1) * sizeof(int));
    int*   fillpos  = (int*)alloc(N_NODES * sizeof(int));
    int*   deg      = (int*)alloc(N_NODES * sizeof(int));
    int*   chunksum = (int*)alloc(128 * sizeof(int));
    int*   chunkoff = (int*)alloc(128 * sizeof(int));
    int*   gstart   = (int*)alloc((N_GRAPHS + 1) * sizeof(int));
    float* stats    = (float*)alloc(9 * 64 * sizeof(float));
    int*   csr      = (int*)alloc((size_t)N_EDGES * sizeof(int));
    float* hbuf     = (float*)alloc((size_t)N_NODES * 32 * sizeof(float));
    float* sbuf     = (float*)alloc((size_t)N_NODES * 32 * sizeof(float));
    unsigned short* h16 = (unsigned short*)alloc((size_t)N_NODES * 32 * sizeof(unsigned short));

    hipMemsetAsync(deg, 0, N_NODES * sizeof(int), stream);
    hipMemsetAsync(stats, 0, 9 * 64 * sizeof(float), stream);

    // CSR build
    k_hist2<<<256, 256, 0, stream>>>(dstp, deg);
    k_chunksum<<<NCHUNKS, 256, 0, stream>>>(deg, chunksum);
    k_scanchunks<<<1, 128, 0, stream>>>(chunksum, chunkoff, rowptr);
    k_scanfinal<<<NCHUNKS, 256, 0, stream>>>(deg, chunkoff, rowptr, fillpos);
    k_fill2<<<1024, 256, 0, stream>>>(srcp, dstp, fillpos, csr);
    k_bounds<<<3, 256, 0, stream>>>(batch, gstart);

    // ---- Encoder layer 0 (pre-projected) ----
    k_proj128<<<1024, 256, 0, stream>>>(x, e0_w1, hbuf, h16);   // hbuf/h16 = y = x@w1
    k_gather16<<<2048, 256, 0, stream>>>(hbuf, h16, rowptr, csr, sbuf);
    k_mlp0<<<1024, 256, 0, stream>>>(sbuf, e0_b1, e0_w2, e0_b2, stats);
    k_bn<<<4096, 256, 0, stream>>>(sbuf, stats, enc_gamma, enc_beta, hbuf, h16, nullptr);
    k_pool<<<N_GRAPHS, 256, 0, stream>>>(hbuf, gstart, out_global, 0);

    // ---- Encoder layers 1..4 (32 -> 32) ----
    for (int i = 0; i < 4; ++i) {
        float* st = stats + (1 + i) * 64;
        k_gather16<<<2048, 256, 0, stream>>>(hbuf, h16, rowptr, csr, sbuf);
        k_mlp32<<<1024, 256, 0, stream>>>(sbuf,
                                          enc_w1 + i * 1024, enc_b1 + i * 32,
                                          enc_w2 + i * 1024, enc_b2 + i * 32, st);
        k_bn<<<4096, 256, 0, stream>>>(sbuf, st,
                                       enc_gamma + (1 + i) * 32, enc_beta + (1 + i) * 32,
                                       hbuf, h16, (i == 3) ? out_enc : nullptr);
        k_pool<<<N_GRAPHS, 256, 0, stream>>>(hbuf, gstart, out_global, (1 + i) * 32);
    }

    // ---- Decoder layers 0..3 (32 -> 32, BN) ----
    for (int i = 0; i < 4; ++i) {
        float* st = stats + (5 + i) * 64;
        k_gather16<<<2048, 256, 0, stream>>>(hbuf, h16, rowptr, csr, sbuf);
        k_mlp32<<<1024, 256, 0, stream>>>(sbuf,
                                          dec_w1 + i * 1024, dec_b1 + i * 32,
                                          dec_w2 + i * 1024, dec_b2 + i * 32, st);
        k_bn<<<4096, 256, 0, stream>>>(sbuf, st,
                                       dec_gamma + i * 32, dec_beta + i * 32,
                                       hbuf, h16, nullptr);
    }

    // ---- Decoder layer 4 (32 -> 32 -> 128, relu, no BN) ----
    k_gather16<<<2048, 256, 0, stream>>>(hbuf, h16, rowptr, csr, sbuf);
    k_mlp_last<<<1024, 256, 0, stream>>>(sbuf,
                                         dec_w1 + 4 * 1024, dec_b1 + 4 * 32,
                                         dec_w2_last, dec_b2_last, out_dec);
}